// Round 3
// baseline (27.386 us; speedup 1.0000x reference)
//
#include <hip/hip_runtime.h>

#define DIM 512
#define NROWS 65536
#define NBLOCKS 4096   // one-shot: 4 waves/block * 4 rows/wave * 4096 = 65536 rows

// One-shot: each wave owns exactly 4 rows (no loop), so all 8 dwordx4 loads
// issue immediately -> maximal loads-in-flight across the kernel lifetime.
// Lane l covers floats [l*4, l*4+4) and [256 + l*4, ...) of each row.
__global__ __launch_bounds__(256) void nn_dist_kernel(
    const float* __restrict__ x,
    const float* __restrict__ ctx,
    unsigned long long* __restrict__ block_best) {
  const int lane = threadIdx.x & 63;
  const int wave_in_block = threadIdx.x >> 6;
  const int base = (((blockIdx.x << 2) | wave_in_block) << 2);  // 4 rows/wave

  const float* r = ctx + (size_t)base * DIM + lane * 4;
  float4 ca[4], cb[4];
#pragma unroll
  for (int j = 0; j < 4; ++j) {
    ca[j] = *reinterpret_cast<const float4*>(r + j * DIM);
    cb[j] = *reinterpret_cast<const float4*>(r + j * DIM + 256);
  }

  const float4 xa = *reinterpret_cast<const float4*>(x + lane * 4);
  const float4 xb = *reinterpret_cast<const float4*>(x + 256 + lane * 4);

  float s[4];
#pragma unroll
  for (int j = 0; j < 4; ++j) {
    float t = 0.f, d;
    d = ca[j].x - xa.x; t = fmaf(d, d, t);
    d = ca[j].y - xa.y; t = fmaf(d, d, t);
    d = ca[j].z - xa.z; t = fmaf(d, d, t);
    d = ca[j].w - xa.w; t = fmaf(d, d, t);
    d = cb[j].x - xb.x; t = fmaf(d, d, t);
    d = cb[j].y - xb.y; t = fmaf(d, d, t);
    d = cb[j].z - xb.z; t = fmaf(d, d, t);
    d = cb[j].w - xb.w; t = fmaf(d, d, t);
    s[j] = t;
  }
  // 4 independent wave-wide sums; the 6-step chains pipeline.
#pragma unroll
  for (int off = 32; off; off >>= 1) {
#pragma unroll
    for (int j = 0; j < 4; ++j) s[j] += __shfl_xor(s[j], off, 64);
  }

  float best_d = s[0];
  int best_i = base;
#pragma unroll
  for (int j = 1; j < 4; ++j) {
    if (s[j] < best_d) { best_d = s[j]; best_i = base + j; }  // strict < => first idx wins
  }

  // Block-level reduce: 4 waves -> 1 plain store. dist >= 0 so IEEE bits are
  // order-preserving; idx in low bits => smallest idx wins exact ties.
  __shared__ unsigned long long lds[4];
  if (lane == 0) {
    lds[wave_in_block] =
        ((unsigned long long)__float_as_uint(best_d) << 32) | (unsigned)best_i;
  }
  __syncthreads();
  if (threadIdx.x == 0) {
    unsigned long long m = lds[0];
#pragma unroll
    for (int j = 1; j < 4; ++j) m = lds[j] < m ? lds[j] : m;
    block_best[blockIdx.x] = m;
  }
}

// Single block: reduce 4096 candidates, then copy the winning row.
__global__ __launch_bounds__(256) void nn_reduce_copy_kernel(
    const float* __restrict__ ctx,
    const unsigned long long* __restrict__ block_best,
    float* __restrict__ out) {
  __shared__ unsigned long long lds[4];
  __shared__ int s_idx;
  const int t = threadIdx.x;

  unsigned long long m = ~0ull;
#pragma unroll
  for (int k = 0; k < NBLOCKS / 256; ++k) {
    unsigned long long v = block_best[t + (k << 8)];
    m = v < m ? v : m;
  }
#pragma unroll
  for (int off = 32; off; off >>= 1) {
    unsigned long long o = __shfl_xor(m, off, 64);
    m = o < m ? o : m;
  }
  if ((t & 63) == 0) lds[t >> 6] = m;
  __syncthreads();
  if (t == 0) {
    unsigned long long mm = lds[0];
#pragma unroll
    for (int j = 1; j < 4; ++j) mm = lds[j] < mm ? lds[j] : mm;
    s_idx = (int)(unsigned)(mm & 0xFFFFFFFFull);
  }
  __syncthreads();

  const float* src = ctx + (size_t)s_idx * DIM;
  reinterpret_cast<float2*>(out)[t] = reinterpret_cast<const float2*>(src)[t];
}

extern "C" void kernel_launch(void* const* d_in, const int* in_sizes, int n_in,
                              void* d_out, int out_size, void* d_ws, size_t ws_size,
                              hipStream_t stream) {
  const float* x = (const float*)d_in[0];
  const float* ctx = (const float*)d_in[1];
  float* out = (float*)d_out;
  unsigned long long* block_best = (unsigned long long*)d_ws;  // 4096 * 8 B = 32 KiB

  nn_dist_kernel<<<NBLOCKS, 256, 0, stream>>>(x, ctx, block_best);
  nn_reduce_copy_kernel<<<1, 256, 0, stream>>>(ctx, block_best, out);
}